// Round 1
// baseline (685.939 us; speedup 1.0000x reference)
//
#include <hip/hip_runtime.h>
#include <math.h>

#define NN 4096
#define BB 32
#define DD 1024
#define ROWS (BB * DD)

// ---------------------------------------------------------------------------
// k_build_w: w[n] = sqrt(2/N) * ( dw_w[0]/sqrt(2) + sum_{k=1..4} dw_w[k]*cos(pi*(2n+1)k/(2N)) )
// ---------------------------------------------------------------------------
__global__ __launch_bounds__(256) void k_build_w(const float* __restrict__ dw_w,
                                                 float* __restrict__ w) {
    int n = blockIdx.x * 256 + threadIdx.x;
    if (n >= NN) return;
    const float scale     = 0.022097086912079608f;   // sqrt(2/4096)
    const float inv_sqrt2 = 0.7071067811865476f;
    float base = (float)(2 * n + 1) * (float)(M_PI / (2.0 * (double)NN));
    float acc = dw_w[0] * inv_sqrt2;
#pragma unroll
    for (int k = 1; k < 5; ++k) acc += dw_w[k] * cosf(base * (float)k);
    w[n] = acc * scale;
}

// ---------------------------------------------------------------------------
// k_dot: att[row] = dot(x[row, :], w) + dw_b   — one wave (64 lanes) per row.
// 4 waves / 256-thread block, w staged in LDS once per block.
// ---------------------------------------------------------------------------
__global__ __launch_bounds__(256) void k_dot(const float* __restrict__ x,
                                             const float* __restrict__ w,
                                             const float* __restrict__ dw_b,
                                             float* __restrict__ att) {
    __shared__ float ws_lds[NN];
    int t = threadIdx.x;
    // cooperative load of w into LDS (4096 floats = 1024 float4, 256 threads x 4)
#pragma unroll
    for (int i = 0; i < 4; ++i) {
        ((float4*)ws_lds)[t + i * 256] = ((const float4*)w)[t + i * 256];
    }
    __syncthreads();

    int wave = t >> 6, lane = t & 63;
    int row  = blockIdx.x * 4 + wave;           // grid = ROWS/4 = 8192
    const float4* xr = (const float4*)(x + (size_t)row * NN);
    const float4* wr = (const float4*)ws_lds;

    float a0 = 0.f, a1 = 0.f, a2 = 0.f, a3 = 0.f;
#pragma unroll
    for (int it = 0; it < 16; ++it) {
        float4 xv = xr[it * 64 + lane];
        float4 wv = wr[it * 64 + lane];
        a0 += xv.x * wv.x;
        a1 += xv.y * wv.y;
        a2 += xv.z * wv.z;
        a3 += xv.w * wv.w;
    }
    float acc = (a0 + a1) + (a2 + a3);
#pragma unroll
    for (int off = 32; off; off >>= 1) acc += __shfl_xor(acc, off);
    if (lane == 0) att[row] = acc + dw_b[0];
}

// ---------------------------------------------------------------------------
// k_stats: global mean and rstd over all 32768 att values (single block).
// ---------------------------------------------------------------------------
__global__ __launch_bounds__(1024) void k_stats(const float* __restrict__ att,
                                                float* __restrict__ stats) {
    __shared__ float s_sum[16], s_ss[16];
    float s = 0.f, ss = 0.f;
    for (int i = threadIdx.x; i < ROWS; i += 1024) {
        float v = att[i];
        s += v;
        ss += v * v;
    }
#pragma unroll
    for (int off = 32; off; off >>= 1) {
        s  += __shfl_xor(s, off);
        ss += __shfl_xor(ss, off);
    }
    int lane = threadIdx.x & 63, wid = threadIdx.x >> 6;
    if (lane == 0) { s_sum[wid] = s; s_ss[wid] = ss; }
    __syncthreads();
    if (threadIdx.x == 0) {
        float ts = 0.f, tss = 0.f;
#pragma unroll
        for (int i = 0; i < 16; ++i) { ts += s_sum[i]; tss += s_ss[i]; }
        float mean = ts * (1.f / ROWS);
        float var  = tss * (1.f / ROWS) - mean * mean;
        stats[0] = mean;
        stats[1] = rsqrtf(var + 1e-5f);
    }
}

// ---------------------------------------------------------------------------
// k_softmax: per-b row of D=1024 — BN affine + exact GELU + conv affine +
// softmax; writes p and 1-p.
// ---------------------------------------------------------------------------
__global__ __launch_bounds__(1024) void k_softmax(const float* __restrict__ att,
                                                  const float* __restrict__ stats,
                                                  const float* __restrict__ gamma,
                                                  const float* __restrict__ beta,
                                                  const float* __restrict__ conv_w,
                                                  const float* __restrict__ conv_b,
                                                  float* __restrict__ out) {
    __shared__ float red[16];
    int b = blockIdx.x, d = threadIdx.x;
    float mean = stats[0], rstd = stats[1];
    float v = att[b * DD + d];
    v = (v - mean) * rstd * gamma[0] + beta[0];
    float g  = 0.5f * v * (1.f + erff(v * 0.7071067811865476f));  // exact gelu
    float a1 = g * conv_w[0] + conv_b[0];

    int lane = d & 63, wid = d >> 6;
    // block max
    float m = a1;
#pragma unroll
    for (int off = 32; off; off >>= 1) m = fmaxf(m, __shfl_xor(m, off));
    if (lane == 0) red[wid] = m;
    __syncthreads();
    float bm = red[0];
#pragma unroll
    for (int i = 1; i < 16; ++i) bm = fmaxf(bm, red[i]);
    float e = expf(a1 - bm);
    __syncthreads();   // before reusing red[]
    // block sum
    float s = e;
#pragma unroll
    for (int off = 32; off; off >>= 1) s += __shfl_xor(s, off);
    if (lane == 0) red[wid] = s;
    __syncthreads();
    float bs = 0.f;
#pragma unroll
    for (int i = 0; i < 16; ++i) bs += red[i];

    float p = e / bs;
    out[b * DD + d]        = p;
    out[ROWS + b * DD + d] = 1.f - p;
}

// ---------------------------------------------------------------------------
extern "C" void kernel_launch(void* const* d_in, const int* in_sizes, int n_in,
                              void* d_out, int out_size, void* d_ws, size_t ws_size,
                              hipStream_t stream) {
    const float* x      = (const float*)d_in[0];
    const float* dw_w   = (const float*)d_in[1];
    const float* dw_b   = (const float*)d_in[2];
    const float* gamma  = (const float*)d_in[3];
    const float* beta   = (const float*)d_in[4];
    const float* conv_w = (const float*)d_in[5];
    const float* conv_b = (const float*)d_in[6];
    float* out = (float*)d_out;

    float* wsf   = (float*)d_ws;
    float* w     = wsf;                 // 4096 floats
    float* att   = wsf + NN;            // 32768 floats
    float* stats = wsf + NN + ROWS;     // 2 floats

    k_build_w<<<NN / 256, 256, 0, stream>>>(dw_w, w);
    k_dot<<<ROWS / 4, 256, 0, stream>>>(x, w, dw_b, att);
    k_stats<<<1, 1024, 0, stream>>>(att, stats);
    k_softmax<<<BB, 1024, 0, stream>>>(att, stats, gamma, beta, conv_w, conv_b, out);
}